// Round 6
// baseline (426.614 us; speedup 1.0000x reference)
//
#include <hip/hip_runtime.h>
#include <hip/hip_bf16.h>

#define NPTS 131072
#define MCB  512
#define DIM  128
#define NRB  1024   // 128-row blocks

typedef __attribute__((ext_vector_type(4))) float  f32x4;
typedef __attribute__((ext_vector_type(8))) __bf16 bf16x8;
typedef unsigned short u16;
typedef unsigned int   u32;

// f32 rows (len 128) -> bf16 + per-row sum of squares of the ROUNDED values.
// (Used for S only; X conversion is fused into pass1.)
__global__ __launch_bounds__(256) void convert_rows(const float* __restrict__ in,
                                                    u16* __restrict__ outb,
                                                    float* __restrict__ sq,
                                                    int nrows) {
  int wv = threadIdx.x >> 6, ln = threadIdx.x & 63;
  int half = ln >> 5, li = ln & 31;
  int npairs = nrows >> 1;
  for (int pr = blockIdx.x * 4 + wv; pr < npairs; pr += gridDim.x * 4) {
    int row = pr * 2 + half;
    const float4 v = *(const float4*)(in + (size_t)row * DIM + li * 4);
    __hip_bfloat16 b0 = __float2bfloat16(v.x);
    __hip_bfloat16 b1 = __float2bfloat16(v.y);
    __hip_bfloat16 b2 = __float2bfloat16(v.z);
    __hip_bfloat16 b3 = __float2bfloat16(v.w);
    ushort4 o;
    o.x = *(const u16*)&b0; o.y = *(const u16*)&b1;
    o.z = *(const u16*)&b2; o.w = *(const u16*)&b3;
    *(ushort4*)(outb + (size_t)row * DIM + li * 4) = o;
    float f0 = __bfloat162float(b0), f1 = __bfloat162float(b1);
    float f2 = __bfloat162float(b2), f3 = __bfloat162float(b3);
    float s = f0 * f0 + f1 * f1 + f2 * f2 + f3 * f3;
    s += __shfl_xor(s, 1); s += __shfl_xor(s, 2); s += __shfl_xor(s, 4);
    s += __shfl_xor(s, 8); s += __shfl_xor(s, 16);
    if (li == 0) sq[row] = s;
  }
}

// Pass 1: block rb handles a 128x512 band. Phase A: convert its 128 X rows
// f32->bf16 (write Xb + x2). Phase B: for each of 4 col-blocks, MFMA with
// operands loaded DIRECT global->VGPR (Sb is L1/L2-resident; Xb rows are this
// block's own, L1/L2-hot), then column partial sums of exp(-dist).
__global__ __launch_bounds__(256, 2) void pass1(const float* __restrict__ X,
                                                const u16* __restrict__ Sb,
                                                const float* __restrict__ s2,
                                                u16* __restrict__ Xb,
                                                float* __restrict__ x2,
                                                float* __restrict__ partial) {
  __shared__ float colsum2[4][64];
  int t = threadIdx.x, wv = t >> 6, ln = t & 63;
  u32 h = blockIdx.x;
  u32 rb = (h & 7u) * (NRB / 8) + (h >> 3);   // bijective XCD chunking
  u32 n0 = rb * 128;

  // ---- Phase A: convert 128 rows (64 pairs; wave handles 2 rows/iter) ----
  {
    int half = ln >> 5, li = ln & 31;
    const float* Xblk = X + (size_t)n0 * DIM;
    u16* Xbblk = Xb + (size_t)n0 * DIM;
#pragma unroll
    for (int it = 0; it < 16; ++it) {
      int row = (it * 4 + wv) * 2 + half;   // 0..127
      const float4 v = *(const float4*)(Xblk + (size_t)row * DIM + li * 4);
      __hip_bfloat16 b0 = __float2bfloat16(v.x);
      __hip_bfloat16 b1 = __float2bfloat16(v.y);
      __hip_bfloat16 b2 = __float2bfloat16(v.z);
      __hip_bfloat16 b3 = __float2bfloat16(v.w);
      ushort4 o;
      o.x = *(const u16*)&b0; o.y = *(const u16*)&b1;
      o.z = *(const u16*)&b2; o.w = *(const u16*)&b3;
      *(ushort4*)(Xbblk + (size_t)row * DIM + li * 4) = o;
      float f0 = __bfloat162float(b0), f1 = __bfloat162float(b1);
      float f2 = __bfloat162float(b2), f3 = __bfloat162float(b3);
      float s = f0 * f0 + f1 * f1 + f2 * f2 + f3 * f3;
      s += __shfl_xor(s, 1); s += __shfl_xor(s, 2); s += __shfl_xor(s, 4);
      s += __shfl_xor(s, 8); s += __shfl_xor(s, 16);
      if (li == 0) x2[n0 + row] = s;
    }
  }
  __syncthreads();   // drains vmcnt; same-CU L1 is coherent with own writes

  // ---- Phase B ----
  int wr = wv >> 1, wc = wv & 1;
  int rbw = wr * 64, cbw = wc * 64;
  int lr = ln & 15, lg = ln >> 4;

  bf16x8 af[4][4];
  const u16* Ab = Xb + (size_t)(n0 + rbw) * DIM;
#pragma unroll
  for (int i = 0; i < 4; i++)
#pragma unroll
    for (int kk = 0; kk < 4; kk++)
      af[i][kk] = *(const bf16x8*)(Ab + (i * 16 + lr) * DIM + kk * 32 + lg * 8);

  f32x4 lxv[4];
#pragma unroll
  for (int i = 0; i < 4; i++)
    lxv[i] = *(const f32x4*)(x2 + n0 + rbw + i * 16 + lg * 4);

#pragma unroll
  for (int cb = 0; cb < 4; ++cb) {
    int m0c = cb * 128;
    f32x4 acc[4][4];
#pragma unroll
    for (int i = 0; i < 4; i++)
#pragma unroll
      for (int j = 0; j < 4; j++) acc[i][j] = (f32x4){0.f, 0.f, 0.f, 0.f};

#pragma unroll
    for (int kk = 0; kk < 4; kk++) {
      bf16x8 bb[4];
#pragma unroll
      for (int j = 0; j < 4; j++)
        bb[j] = *(const bf16x8*)(Sb + (size_t)(m0c + cbw + j * 16 + lr) * DIM + kk * 32 + lg * 8);
#pragma unroll
      for (int i = 0; i < 4; i++)
#pragma unroll
        for (int j = 0; j < 4; j++)
          acc[i][j] = __builtin_amdgcn_mfma_f32_16x16x32_bf16(af[i][kk], bb[j], acc[i][j], 0, 0, 0);
    }

    // D layout: row -> n = rbw+i*16+lg*4+r, col=lane&15 -> m = cbw+j*16+lr.
    float s2v[4];
#pragma unroll
    for (int j = 0; j < 4; j++) s2v[j] = s2[m0c + cbw + j * 16 + lr];
    float csum[4] = {0.f, 0.f, 0.f, 0.f};
#pragma unroll
    for (int i = 0; i < 4; i++)
#pragma unroll
      for (int j = 0; j < 4; j++)
#pragma unroll
        for (int r = 0; r < 4; r++) {
          float d2 = lxv[i][r] + s2v[j] - 2.f * acc[i][j][r];
          d2 = fmaxf(d2, 0.f);
          csum[j] += __expf(-__fsqrt_rn(d2));
        }
#pragma unroll
    for (int j = 0; j < 4; j++) {
      float v = csum[j];
      v += __shfl_xor(v, 16);
      v += __shfl_xor(v, 32);
      if (ln < 16) colsum2[wv][j * 16 + ln] = v;
    }
    __syncthreads();
    if (t < 128) {
      int wcf = t >> 6, lc = t & 63;
      partial[(size_t)rb * MCB + m0c + t] = colsum2[wcf][lc] + colsum2[wcf + 2][lc];
    }
    __syncthreads();
  }
}

// Sum the 1024 per-row-block partials per column, emit 1/sum. Deterministic.
// Block b handles 8 columns; lanes contiguous in m for coalescing.
__global__ __launch_bounds__(256) void reduce_cols(const float* __restrict__ partial,
                                                   float* __restrict__ invs) {
  int b = blockIdx.x, t = threadIdx.x, ln = t & 63, wv = t >> 6;
  int m = b * 8 + (t & 7);
  float s = 0.f;
  for (int k = t >> 3; k < NRB; k += 32) s += partial[(size_t)k * MCB + m];
  s += __shfl_xor(s, 8); s += __shfl_xor(s, 16); s += __shfl_xor(s, 32);
  __shared__ float red[4][8];
  if (ln < 8) red[wv][ln] = s;
  __syncthreads();
  if (t < 8) invs[b * 8 + t] = 1.0f / (red[0][t] + red[1][t] + red[2][t] + red[3][t]);
}

// Pass 2: block rb re-computes its 128x512 band with swapped-operand MFMA
// (D-row -> m: 4 consecutive m per lane) and writes normalized exp via
// nontemporal dwordx4. No LDS, no barriers.
__global__ __launch_bounds__(256, 2) void pass2(const u16* __restrict__ Xb,
                                                const u16* __restrict__ Sb,
                                                const float* __restrict__ x2,
                                                const float* __restrict__ s2,
                                                const float* __restrict__ invs,
                                                float* __restrict__ out) {
  int t = threadIdx.x, wv = t >> 6, ln = t & 63;
  u32 h = blockIdx.x;
  u32 rb = (h & 7u) * (NRB / 8) + (h >> 3);   // same mapping as pass1 -> same XCD
  u32 n0 = rb * 128;

  int wr = wv >> 1, wc = wv & 1;
  int rbw = wr * 64, cbw = wc * 64;
  int lr = ln & 15, lg = ln >> 4;

  bf16x8 af[4][4];
  const u16* Ab = Xb + (size_t)(n0 + rbw) * DIM;
#pragma unroll
  for (int i = 0; i < 4; i++)
#pragma unroll
    for (int kk = 0; kk < 4; kk++)
      af[i][kk] = *(const bf16x8*)(Ab + (i * 16 + lr) * DIM + kk * 32 + lg * 8);

  float xx[4];
#pragma unroll
  for (int i = 0; i < 4; i++) xx[i] = x2[n0 + rbw + i * 16 + lr];

#pragma unroll
  for (int cb = 0; cb < 4; ++cb) {
    int m0c = cb * 128;
    f32x4 acc[4][4];
#pragma unroll
    for (int i = 0; i < 4; i++)
#pragma unroll
      for (int j = 0; j < 4; j++) acc[i][j] = (f32x4){0.f, 0.f, 0.f, 0.f};

#pragma unroll
    for (int kk = 0; kk < 4; kk++) {
      bf16x8 bb[4];
#pragma unroll
      for (int j = 0; j < 4; j++)
        bb[j] = *(const bf16x8*)(Sb + (size_t)(m0c + cbw + j * 16 + lr) * DIM + kk * 32 + lg * 8);
#pragma unroll
      for (int i = 0; i < 4; i++)
#pragma unroll
        for (int j = 0; j < 4; j++)
          acc[i][j] = __builtin_amdgcn_mfma_f32_16x16x32_bf16(bb[j], af[i][kk], acc[i][j], 0, 0, 0);
    }

    // Swapped D layout: row=(lg*4+r) -> m = cbw+j*16+lg*4+r, col=lr -> n.
    f32x4 ls2v[4], lscv[4];
#pragma unroll
    for (int j = 0; j < 4; j++) {
      ls2v[j] = *(const f32x4*)(s2  + m0c + cbw + j * 16 + lg * 4);
      lscv[j] = *(const f32x4*)(invs + m0c + cbw + j * 16 + lg * 4);
    }
#pragma unroll
    for (int i = 0; i < 4; i++) {
      float xxi = xx[i];
      float* orow = out + (size_t)(n0 + rbw + i * 16 + lr) * MCB + m0c;
#pragma unroll
      for (int j = 0; j < 4; j++) {
        f32x4 v;
#pragma unroll
        for (int r = 0; r < 4; r++) {
          float d2 = xxi + ls2v[j][r] - 2.f * acc[i][j][r];
          d2 = fmaxf(d2, 0.f);
          v[r] = __expf(-__fsqrt_rn(d2)) * lscv[j][r];
        }
        __builtin_nontemporal_store(v, (f32x4*)(orow + cbw + j * 16 + lg * 4));
      }
    }
  }
}

extern "C" void kernel_launch(void* const* d_in, const int* in_sizes, int n_in,
                              void* d_out, int out_size, void* d_ws, size_t ws_size,
                              hipStream_t stream) {
  const float* X = (const float*)d_in[0];
  const float* S = (const float*)d_in[1];
  float* out = (float*)d_out;
  char* ws = (char*)d_ws;

  // ws layout (256B-aligned), total ~36.3 MB:
  u16*   Xb      = (u16*)ws;                      // 131072*128*2 = 33554432
  u16*   Sb      = (u16*)(ws + 33554432);         // 512*128*2    = 131072
  float* x2      = (float*)(ws + 33685504);       // 131072*4     = 524288
  float* s2      = (float*)(ws + 34209792);       // 512*4        = 2048
  float* invs    = (float*)(ws + 34211840);       // 512*4        = 2048
  float* partial = (float*)(ws + 34213888);       // 1024*512*4   = 2097152

  convert_rows<<<64, 256, 0, stream>>>(S, Sb, s2, MCB);
  pass1<<<NRB, 256, 0, stream>>>(X, Sb, s2, Xb, x2, partial);
  reduce_cols<<<64, 256, 0, stream>>>(partial, invs);
  pass2<<<NRB, 256, 0, stream>>>(Xb, Sb, x2, s2, invs, out);
}

// Round 7
// 397.889 us; speedup vs baseline: 1.0722x; 1.0722x over previous
//
#include <hip/hip_runtime.h>
#include <hip/hip_bf16.h>

#define NPTS 131072
#define MCB  512
#define DIM  128
#define NRB  (NPTS/128)   // 1024 row blocks
#define NCBK (MCB/128)    // 4 col blocks
#define NBLK (NRB*NCBK)   // 4096 blocks

typedef __attribute__((ext_vector_type(4))) float  f32x4;
typedef __attribute__((ext_vector_type(8))) __bf16 bf16x8;
typedef unsigned short u16;
typedef unsigned int   u32;

// XOR-swizzle: permute 16B chunks within each 256B row by row&7. Involution.
__device__ __forceinline__ u32 swz(u32 p) { return p ^ (((p >> 8) & 7u) << 4); }

// f32 rows (len 128) -> bf16 + per-row sum of squares of the ROUNDED values.
__global__ __launch_bounds__(256) void convert_rows(const float* __restrict__ in,
                                                    u16* __restrict__ outb,
                                                    float* __restrict__ sq,
                                                    int nrows) {
  int wv = threadIdx.x >> 6, ln = threadIdx.x & 63;
  int half = ln >> 5, li = ln & 31;
  int npairs = nrows >> 1;
  for (int pr = blockIdx.x * 4 + wv; pr < npairs; pr += gridDim.x * 4) {
    int row = pr * 2 + half;
    const float4 v = *(const float4*)(in + (size_t)row * DIM + li * 4);
    __hip_bfloat16 b0 = __float2bfloat16(v.x);
    __hip_bfloat16 b1 = __float2bfloat16(v.y);
    __hip_bfloat16 b2 = __float2bfloat16(v.z);
    __hip_bfloat16 b3 = __float2bfloat16(v.w);
    ushort4 o;
    o.x = *(const u16*)&b0; o.y = *(const u16*)&b1;
    o.z = *(const u16*)&b2; o.w = *(const u16*)&b3;
    *(ushort4*)(outb + (size_t)row * DIM + li * 4) = o;
    float f0 = __bfloat162float(b0), f1 = __bfloat162float(b1);
    float f2 = __bfloat162float(b2), f3 = __bfloat162float(b3);
    float s = f0 * f0 + f1 * f1 + f2 * f2 + f3 * f3;
    s += __shfl_xor(s, 1); s += __shfl_xor(s, 2); s += __shfl_xor(s, 4);
    s += __shfl_xor(s, 8); s += __shfl_xor(s, 16);
    if (li == 0) sq[row] = s;
  }
}

// One block = 128x128 output tile; K=128 fits in one LDS tile (no K loop).
// A and B both staged via global_load_lds (coalesced 1KB/instr), swizzled.
// 4 waves in 2x2, each owns 64x64 (4x4 fragments of 16x16, 4 k-steps of 32).
// WRITE=0: mfma(af,bfr): D row->n, col->m. Column sums of exp(-dist) -> partial.
// WRITE=1: mfma(bfr,af): D row->m (4 consecutive m/lane) -> f32x4 NT stores.
template <int WRITE>
__global__ __launch_bounds__(256, 2) void gemm_pass(const u16* __restrict__ Xb,
                                                    const u16* __restrict__ Sb,
                                                    const float* __restrict__ x2,
                                                    const float* __restrict__ s2,
                                                    const float* __restrict__ invs,
                                                    float* __restrict__ outp) {
  __shared__ u16 At[128 * DIM];   // 32 KB, swizzled storage
  __shared__ u16 Bt[128 * DIM];   // 32 KB
  __shared__ alignas(16) float lx2[128], ls2[128], lscale[128];
  __shared__ float colsum2[4][64];

  int t = threadIdx.x, wv = t >> 6, ln = t & 63;
  u32 h = blockIdx.x;
  u32 l = (h & 7u) * (NBLK / 8) + (h >> 3);   // bijective XCD chunking
  u32 rb = l >> 2, cb = l & 3u;
  u32 n0 = rb * 128, m0 = cb * 128;

  // Stage A/B tiles: pre-swizzled GLOBAL source, linear LDS dest.
  const char* Ag = (const char*)(Xb + (size_t)n0 * DIM);
  const char* Bg = (const char*)(Sb + (size_t)m0 * DIM);
#pragma unroll
  for (int i = 0; i < 8; i++) {
    u32 lb = (u32)(i * 4 + wv) * 1024u;   // wave-uniform LDS base
    u32 go = swz(lb + (u32)ln * 16u);     // per-lane swizzled global offset
    __builtin_amdgcn_global_load_lds((const __attribute__((address_space(1))) void*)(Ag + go),
                                     (__attribute__((address_space(3))) void*)((char*)At + lb),
                                     16, 0, 0);
    __builtin_amdgcn_global_load_lds((const __attribute__((address_space(1))) void*)(Bg + go),
                                     (__attribute__((address_space(3))) void*)((char*)Bt + lb),
                                     16, 0, 0);
  }
  if (t < 128) {
    lx2[t] = x2[n0 + t];
    ls2[t] = s2[m0 + t];
    if (WRITE) lscale[t] = invs[m0 + t];
  }
  __syncthreads();

  int wr = wv >> 1, wc = wv & 1;
  int rbw = wr * 64, cbw = wc * 64;
  int lr = ln & 15, lg = ln >> 4;

  f32x4 acc[4][4];
#pragma unroll
  for (int i = 0; i < 4; i++)
#pragma unroll
    for (int j = 0; j < 4; j++) acc[i][j] = (f32x4){0.f, 0.f, 0.f, 0.f};

#pragma unroll
  for (int kk = 0; kk < 4; kk++) {
    bf16x8 af[4], bfr[4];
#pragma unroll
    for (int i = 0; i < 4; i++)
      af[i] = *(const bf16x8*)((const char*)At +
               swz((u32)((rbw + i * 16 + lr) * 256 + kk * 64 + lg * 16)));
#pragma unroll
    for (int j = 0; j < 4; j++)
      bfr[j] = *(const bf16x8*)((const char*)Bt +
               swz((u32)((cbw + j * 16 + lr) * 256 + kk * 64 + lg * 16)));
#pragma unroll
    for (int i = 0; i < 4; i++)
#pragma unroll
      for (int j = 0; j < 4; j++) {
        if (WRITE)
          acc[i][j] = __builtin_amdgcn_mfma_f32_16x16x32_bf16(bfr[j], af[i], acc[i][j], 0, 0, 0);
        else
          acc[i][j] = __builtin_amdgcn_mfma_f32_16x16x32_bf16(af[i], bfr[j], acc[i][j], 0, 0, 0);
      }
  }

  if (WRITE) {
    // Swapped D layout: row=(lane>>4)*4+reg -> m, col=lane&15 -> n.
    f32x4 ls2v[4], lscv[4];
#pragma unroll
    for (int j = 0; j < 4; j++) {
      ls2v[j] = *(const f32x4*)(&ls2[cbw + j * 16 + lg * 4]);
      lscv[j] = *(const f32x4*)(&lscale[cbw + j * 16 + lg * 4]);
    }
#pragma unroll
    for (int i = 0; i < 4; i++) {
      int n = rbw + i * 16 + lr;
      float xx = lx2[n];
      float* orow = outp + (size_t)(n0 + n) * MCB + m0;
#pragma unroll
      for (int j = 0; j < 4; j++) {
        f32x4 v;
#pragma unroll
        for (int r = 0; r < 4; r++) {
          float d2 = xx + ls2v[j][r] - 2.f * acc[i][j][r];
          d2 = fmaxf(d2, 0.f);
          v[r] = __expf(-__fsqrt_rn(d2)) * lscv[j][r];
        }
        __builtin_nontemporal_store(v, (f32x4*)(orow + cbw + j * 16 + lg * 4));
      }
    }
  } else {
    // Normal D layout: row -> n (in-lane over r), col=lane&15 -> m.
    float csum[4] = {0.f, 0.f, 0.f, 0.f};
#pragma unroll
    for (int i = 0; i < 4; i++) {
#pragma unroll
      for (int j = 0; j < 4; j++) {
        int m = cbw + j * 16 + lr;
        float ss = ls2[m];
#pragma unroll
        for (int r = 0; r < 4; r++) {
          int n = rbw + i * 16 + lg * 4 + r;
          float d2 = lx2[n] + ss - 2.f * acc[i][j][r];
          d2 = fmaxf(d2, 0.f);
          csum[j] += __expf(-__fsqrt_rn(d2));
        }
      }
    }
    // Reduce across the 4 lane-groups (bits 4,5); lanes 0..15 hold col sums.
#pragma unroll
    for (int j = 0; j < 4; j++) {
      float v = csum[j];
      v += __shfl_xor(v, 16);
      v += __shfl_xor(v, 32);
      if (ln < 16) colsum2[wv][j * 16 + ln] = v;
    }
    __syncthreads();
    if (t < 128) {
      int wcf = t >> 6, lc = t & 63;
      outp[(size_t)rb * MCB + m0 + t] = colsum2[wcf][lc] + colsum2[wcf + 2][lc];
    }
  }
}

// Sum the 1024 per-row-block partials per column, emit 1/sum. Deterministic.
// Block b handles 8 columns; lanes contiguous in m for coalescing.
__global__ __launch_bounds__(256) void reduce_cols(const float* __restrict__ partial,
                                                   float* __restrict__ invs) {
  int b = blockIdx.x, t = threadIdx.x, ln = t & 63, wv = t >> 6;
  int m = b * 8 + (t & 7);
  float s = 0.f;
  for (int k = t >> 3; k < NRB; k += 32) s += partial[(size_t)k * MCB + m];
  s += __shfl_xor(s, 8); s += __shfl_xor(s, 16); s += __shfl_xor(s, 32);
  __shared__ float red[4][8];
  if (ln < 8) red[wv][ln] = s;
  __syncthreads();
  if (t < 8) invs[b * 8 + t] = 1.0f / (red[0][t] + red[1][t] + red[2][t] + red[3][t]);
}

extern "C" void kernel_launch(void* const* d_in, const int* in_sizes, int n_in,
                              void* d_out, int out_size, void* d_ws, size_t ws_size,
                              hipStream_t stream) {
  const float* X = (const float*)d_in[0];
  const float* S = (const float*)d_in[1];
  float* out = (float*)d_out;
  char* ws = (char*)d_ws;

  // ws layout (256B-aligned), total ~36.3 MB:
  u16*   Xb      = (u16*)ws;                      // 131072*128*2 = 33554432
  u16*   Sb      = (u16*)(ws + 33554432);         // 512*128*2    = 131072
  float* x2      = (float*)(ws + 33685504);       // 131072*4     = 524288
  float* s2      = (float*)(ws + 34209792);       // 512*4        = 2048
  float* invs    = (float*)(ws + 34211840);       // 512*4        = 2048
  float* partial = (float*)(ws + 34213888);       // 1024*512*4   = 2097152

  convert_rows<<<2048, 256, 0, stream>>>(X, Xb, x2, NPTS);
  convert_rows<<<64, 256, 0, stream>>>(S, Sb, s2, MCB);
  gemm_pass<0><<<NBLK, 256, 0, stream>>>(Xb, Sb, x2, s2, invs, partial);
  reduce_cols<<<64, 256, 0, stream>>>(partial, invs);
  gemm_pass<1><<<NBLK, 256, 0, stream>>>(Xb, Sb, x2, s2, invs, out);
}

// Round 8
// 392.418 us; speedup vs baseline: 1.0871x; 1.0139x over previous
//
#include <hip/hip_runtime.h>
#include <hip/hip_bf16.h>

#define NPTS 131072
#define MCB  512
#define DIM  128
#define NRB  (NPTS/128)   // 1024 row blocks
#define NCBK (MCB/128)    // 4 col blocks
#define NBLK (NRB*NCBK)   // 4096 blocks

typedef __attribute__((ext_vector_type(4))) float  f32x4;
typedef __attribute__((ext_vector_type(8))) __bf16 bf16x8;
typedef unsigned short u16;
typedef unsigned int   u32;

// XOR-swizzle: permute 16B chunks within each 256B row by row&7. Involution.
__device__ __forceinline__ u32 swz(u32 p) { return p ^ (((p >> 8) & 7u) << 4); }

// f32 rows (len 128) -> bf16 + per-row sum of squares of the ROUNDED values.
__global__ __launch_bounds__(256) void convert_rows(const float* __restrict__ in,
                                                    u16* __restrict__ outb,
                                                    float* __restrict__ sq,
                                                    int nrows) {
  int wv = threadIdx.x >> 6, ln = threadIdx.x & 63;
  int half = ln >> 5, li = ln & 31;
  int npairs = nrows >> 1;
  for (int pr = blockIdx.x * 4 + wv; pr < npairs; pr += gridDim.x * 4) {
    int row = pr * 2 + half;
    const float4 v = *(const float4*)(in + (size_t)row * DIM + li * 4);
    __hip_bfloat16 b0 = __float2bfloat16(v.x);
    __hip_bfloat16 b1 = __float2bfloat16(v.y);
    __hip_bfloat16 b2 = __float2bfloat16(v.z);
    __hip_bfloat16 b3 = __float2bfloat16(v.w);
    ushort4 o;
    o.x = *(const u16*)&b0; o.y = *(const u16*)&b1;
    o.z = *(const u16*)&b2; o.w = *(const u16*)&b3;
    *(ushort4*)(outb + (size_t)row * DIM + li * 4) = o;
    float f0 = __bfloat162float(b0), f1 = __bfloat162float(b1);
    float f2 = __bfloat162float(b2), f3 = __bfloat162float(b3);
    float s = f0 * f0 + f1 * f1 + f2 * f2 + f3 * f3;
    s += __shfl_xor(s, 1); s += __shfl_xor(s, 2); s += __shfl_xor(s, 4);
    s += __shfl_xor(s, 8); s += __shfl_xor(s, 16);
    if (li == 0) sq[row] = s;
  }
}

// One block = 128x128 output tile; K=128, no K loop.
// B staged via global_load_lds (swizzled, 32 KB); A fragments DIRECT
// global->VGPR (measured neutral vs LDS, frees LDS for occupancy 3).
// WRITE=0: mfma(af,bfr), column sums of exp(-dist) -> partial (atomicAdd, R1).
// WRITE=1: mfma(af,bfr), R1 scalar-store epilogue (4x64B segments/instr).
template <int WRITE>
__global__ __launch_bounds__(256, 3) void gemm_pass(const u16* __restrict__ Xb,
                                                    const u16* __restrict__ Sb,
                                                    const float* __restrict__ x2,
                                                    const float* __restrict__ s2,
                                                    const float* __restrict__ invs,
                                                    float* __restrict__ outp) {
  __shared__ u16 Bt[128 * DIM];   // 32 KB, swizzled storage
  __shared__ float lx2[128], ls2[128], lscale[128], colsum[128];

  int t = threadIdx.x, wv = t >> 6, ln = t & 63;
  u32 h = blockIdx.x;
  u32 l = (h & 7u) * (NBLK / 8) + (h >> 3);   // bijective XCD chunking
  u32 rb = l >> 2, cb = l & 3u;
  u32 n0 = rb * 128, m0 = cb * 128;

  // Stage B tile: pre-swizzled GLOBAL source, linear LDS dest.
  const char* Bg = (const char*)(Sb + (size_t)m0 * DIM);
#pragma unroll
  for (int i = 0; i < 8; i++) {
    u32 lb = (u32)(i * 4 + wv) * 1024u;   // wave-uniform LDS base
    u32 go = swz(lb + (u32)ln * 16u);     // per-lane swizzled global offset
    __builtin_amdgcn_global_load_lds((const __attribute__((address_space(1))) void*)(Bg + go),
                                     (__attribute__((address_space(3))) void*)((char*)Bt + lb),
                                     16, 0, 0);
  }
  if (t < 128) {
    lx2[t] = x2[n0 + t];
    ls2[t] = s2[m0 + t];
    if (WRITE) lscale[t] = invs[m0 + t];
    else       colsum[t] = 0.f;
  }

  int wr = wv >> 1, wc = wv & 1;
  int rbw = wr * 64, cbw = wc * 64;
  int lr = ln & 15, lg = ln >> 4;

  // A fragments direct to registers (Xb is L2/L3-resident).
  bf16x8 af[4][4];
  const u16* Ab = Xb + (size_t)(n0 + rbw) * DIM;
#pragma unroll
  for (int i = 0; i < 4; i++)
#pragma unroll
    for (int kk = 0; kk < 4; kk++)
      af[i][kk] = *(const bf16x8*)(Ab + (i * 16 + lr) * DIM + kk * 32 + lg * 8);

  __syncthreads();

  f32x4 acc[4][4];
#pragma unroll
  for (int i = 0; i < 4; i++)
#pragma unroll
    for (int j = 0; j < 4; j++) acc[i][j] = (f32x4){0.f, 0.f, 0.f, 0.f};

#pragma unroll
  for (int kk = 0; kk < 4; kk++) {
    bf16x8 bfr[4];
#pragma unroll
    for (int j = 0; j < 4; j++)
      bfr[j] = *(const bf16x8*)((const char*)Bt +
               swz((u32)((cbw + j * 16 + lr) * 256 + kk * 64 + lg * 16)));
#pragma unroll
    for (int i = 0; i < 4; i++)
#pragma unroll
      for (int j = 0; j < 4; j++)
        acc[i][j] = __builtin_amdgcn_mfma_f32_16x16x32_bf16(af[i][kk], bfr[j], acc[i][j], 0, 0, 0);
  }

  // Epilogue. C/D layout: col = lane&15 -> m, row = (lane>>4)*4 + reg -> n.
  float csum[4] = {0.f, 0.f, 0.f, 0.f};
#pragma unroll
  for (int i = 0; i < 4; i++) {
#pragma unroll
    for (int j = 0; j < 4; j++) {
      int m = cbw + j * 16 + lr;
      float ss = ls2[m];
#pragma unroll
      for (int r = 0; r < 4; r++) {
        int n = rbw + i * 16 + lg * 4 + r;
        float d2 = lx2[n] + ss - 2.f * acc[i][j][r];
        d2 = fmaxf(d2, 0.f);
        float e = __expf(-__fsqrt_rn(d2));
        if (WRITE) {
          outp[(size_t)(n0 + n) * MCB + (m0 + m)] = e * lscale[m];
        } else {
          csum[j] += e;
        }
      }
    }
  }
  if (!WRITE) {
    // Column m is held by lanes m%16, +16, +32, +48 -> combine via xor-16/32.
#pragma unroll
    for (int j = 0; j < 4; j++) {
      float v = csum[j];
      v += __shfl_xor(v, 16);
      v += __shfl_xor(v, 32);
      if (ln < 16) atomicAdd(&colsum[cbw + j * 16 + ln], v);
    }
    __syncthreads();
    if (t < 128) outp[(size_t)rb * MCB + m0 + t] = colsum[t];  // partial sums
  }
}

// Sum the 1024 per-row-block partials per column, emit 1/sum. Deterministic.
__global__ __launch_bounds__(256) void reduce_cols(const float* __restrict__ partial,
                                                   float* __restrict__ invs) {
  int m = blockIdx.x, t = threadIdx.x;
  float s = 0.f;
  for (int k = t; k < NRB; k += 256) s += partial[(size_t)k * MCB + m];
  s += __shfl_xor(s, 1);  s += __shfl_xor(s, 2);  s += __shfl_xor(s, 4);
  s += __shfl_xor(s, 8);  s += __shfl_xor(s, 16); s += __shfl_xor(s, 32);
  __shared__ float w4[4];
  if ((t & 63) == 0) w4[t >> 6] = s;
  __syncthreads();
  if (t == 0) invs[m] = 1.0f / (w4[0] + w4[1] + w4[2] + w4[3]);
}

extern "C" void kernel_launch(void* const* d_in, const int* in_sizes, int n_in,
                              void* d_out, int out_size, void* d_ws, size_t ws_size,
                              hipStream_t stream) {
  const float* X = (const float*)d_in[0];
  const float* S = (const float*)d_in[1];
  float* out = (float*)d_out;
  char* ws = (char*)d_ws;

  // ws layout (256B-aligned), total ~36.3 MB:
  u16*   Xb      = (u16*)ws;                      // 131072*128*2 = 33554432
  u16*   Sb      = (u16*)(ws + 33554432);         // 512*128*2    = 131072
  float* x2      = (float*)(ws + 33685504);       // 131072*4     = 524288
  float* s2      = (float*)(ws + 34209792);       // 512*4        = 2048
  float* invs    = (float*)(ws + 34211840);       // 512*4        = 2048
  float* partial = (float*)(ws + 34213888);       // 1024*512*4   = 2097152

  convert_rows<<<1024, 256, 0, stream>>>(X, Xb, x2, NPTS);
  convert_rows<<<64, 256, 0, stream>>>(S, Sb, s2, MCB);
  gemm_pass<0><<<NBLK, 256, 0, stream>>>(Xb, Sb, x2, s2, invs, partial);
  reduce_cols<<<MCB, 256, 0, stream>>>(partial, invs);
  gemm_pass<1><<<NBLK, 256, 0, stream>>>(Xb, Sb, x2, s2, invs, out);
}